// Round 3
// baseline (187.096 us; speedup 1.0000x reference)
//
#include <hip/hip_runtime.h>
#include <climits>

#define HW 262144          // 512*512
#define IW 512
#define RN 725             // virtual rotated canvas side
#define NSEG 256
#define CH_OFF 1536
#define TH_OFF 116736
#define XY_OFF 485376
#define NBLK 256           // k_grad tiles per plane; minmax partial count
#define THP 16             // pixel splits in thist
#define CHP 32             // pixel splits in regchist

// grad tile geometry (r16): output tile 64x16; rotated source box 24x72 at (-156,-156).
#define ASTR 67
#define RSTR 73
#define ROFF 156

static __device__ __forceinline__ float rtap_l(const float* __restrict__ Rt,
                                               int rx0, int ry0, int cx, int cy) {
    if (cx < 0 || cx >= RN || cy < 0 || cy >= RN) return 0.f;
    const float cs = 0.7071067811865476f;
    float xg = (float)cx - 362.0f;
    float yg = (float)cy - 362.0f;
    float xi = cs * xg - cs * yg + 255.5f;
    float yi = cs * xg + cs * yg + 255.5f;
    int xs = (int)rintf(xi);
    int ys = (int)rintf(yi);
    if (xs < 0 || xs >= IW || ys < 0 || ys >= IW) return 0.f;
    return Rt[(ys - ry0) * RSTR + (xs - rx0)];
}

// block-level min/max of map m's NBLK partials; all threads get (mn,mx)
static __device__ __forceinline__ void mm_of_map(const float* __restrict__ pmin,
                                                 const float* __restrict__ pmax,
                                                 int m, float* slo, float* shi,
                                                 float& mn, float& mx) {
    int tid = threadIdx.x;
    float lo = 3.4e38f, hi = -3.4e38f;
    for (int i = tid; i < NBLK; i += 256) {
        lo = fminf(lo, pmin[m * NBLK + i]);
        hi = fmaxf(hi, pmax[m * NBLK + i]);
    }
    slo[tid] = lo; shi[tid] = hi;
    __syncthreads();
    for (int off = 128; off > 0; off >>= 1) {
        if (tid < off) {
            slo[tid] = fminf(slo[tid], slo[tid + off]);
            shi[tid] = fmaxf(shi[tid], shi[tid + off]);
        }
        __syncthreads();
    }
    mn = slo[0]; mx = shi[0];
    __syncthreads();
}

// ==== K1: grad (blocks 0..1535) || regchist-partials (blocks 1536..2111) ====
// r17: merged — regchist reads int32 labels (independent of grad's lab8 pack),
// and rs/bbox become deterministic per-block partials (no global atomics, no
// init chores, no intra-kernel ordering assumptions). Integer partial sums in
// fixed order == previous atomic results exactly.
__global__ __launch_bounds__(256) void k_front(
    const float* __restrict__ img, const int* __restrict__ lab,
    float* __restrict__ gmaps, float* __restrict__ pmin, float* __restrict__ pmax,
    unsigned char* __restrict__ lab8, unsigned* __restrict__ chp,
    unsigned* __restrict__ rsp, int* __restrict__ bxmin, int* __restrict__ bxmax,
    int* __restrict__ bymin, int* __restrict__ bymax)
{
    __shared__ __align__(16) char smem[30720];
    int t = blockIdx.x;
    int tid = threadIdx.x;
    if (t < 1536) {
        // ---- grad role: tile (t&255), plane bc=(t>>8) ----
        int tile = t & 255;
        int bc = t >> 8;
        float* At = (float*)smem;                    // 18*67 = 1206 f
        float* Rt = At + 18 * ASTR;                  // 24*73 = 1752 f
        float (*slo)[256] = (float (*)[256])(Rt + 24 * RSTR);  // 4*256 f
        float (*shi)[256] = slo + 4;                 // 4*256 f  (total 20024 B)
        // u8 label pack for thist: 256 blocks/plane * 256 thr * 4 labels == HW
        {
            int i = tile * 256 + tid;
            int4 l = ((const int4*)(lab + (size_t)bc * HW))[i];
            unsigned v = (unsigned)(l.x & 255) | ((unsigned)(l.y & 255) << 8) |
                         ((unsigned)(l.z & 255) << 16) | ((unsigned)(l.w & 255) << 24);
            ((unsigned*)(lab8 + (size_t)bc * HW))[i] = v;
        }
        int tx0 = (tile & 7) << 6;
        int ty0 = (tile >> 3) << 4;
        const float* im = img + (size_t)bc * HW;
        int lane = tid & 63, wr = tid >> 6;
        for (int r = wr; r < 18; r += 4) {
            int gy = ty0 - 1 + r;
            bool yok = (gy >= 0 && gy < IW);
            int gx = tx0 - 1 + lane;
            At[r * ASTR + lane] = (yok && gx >= 0 && gx < IW) ? im[gy * IW + gx] : 0.f;
            if (lane < 2) {
                int gx2 = gx + 64;
                At[r * ASTR + lane + 64] = (yok && gx2 >= 0 && gx2 < IW) ? im[gy * IW + gx2] : 0.f;
            }
        }
        for (int r = wr; r < 24; r += 4) {
            int gy = ty0 - ROFF + r;
            bool yok = (gy >= 0 && gy < IW);
            int gx = tx0 - ROFF + lane;
            Rt[r * RSTR + lane] = (yok && gx >= 0 && gx < IW) ? im[gy * IW + gx] : 0.f;
            if (lane < 8) {
                int gx2 = gx + 64;
                Rt[r * RSTR + lane + 64] = (yok && gx2 >= 0 && gx2 < IW) ? im[gy * IW + gx2] : 0.f;
            }
        }
        __syncthreads();
        const float cs = 0.7071067811865476f;
        int rx0 = tx0 - ROFF, ry0 = ty0 - ROFF;
        float mn0 = 3.4e38f, mx0 = -3.4e38f, mn1 = 3.4e38f, mx1 = -3.4e38f;
        float mn2 = 3.4e38f, mx2 = -3.4e38f, mn3 = 3.4e38f, mx3 = -3.4e38f;
        #pragma unroll
        for (int it = 0; it < 4; ++it) {
            int ly = wr * 4 + it;
            int x = tx0 + lane, y = ty0 + ly;
            int p = y * IW + x;
            const float* Ar = At + ly * ASTR + lane;
            float a  = Ar[0],            b2 = Ar[1],            c2 = Ar[2];
            float d2 = Ar[ASTR],                                 e2 = Ar[ASTR + 2];
            float f2 = Ar[2 * ASTR],     h2 = Ar[2 * ASTR + 1], i9 = Ar[2 * ASTR + 2];
            float g0 = -3.f*a + 3.f*c2 + 10.f*d2 + 10.f*e2 - 3.f*f2 + 3.f*i9;
            float g1 = -3.f*a + 10.f*b2 - 3.f*c2 + 3.f*f2 + 10.f*h2 + 3.f*i9;
            gmaps[((size_t)(bc*2+0))*HW + p] = g0;
            gmaps[((size_t)(bc*2+1))*HW + p] = g1;
            float xgc = (float)(x + 105) - 512.5f;
            float ygc = (float)(y + 105) - 512.5f;
            float t1 = cs * xgc, t2 = cs * ygc;
            float xi = (t1 + t2) + 362.0f;
            float yi = (-t1 + t2) + 362.0f;
            int xn = (int)rintf(xi);
            int yn = (int)rintf(yi);
            float r0 = 0.f, r1 = 0.f;
            if (xn >= 0 && xn < RN && yn >= 0 && yn < RN) {
                float ra = rtap_l(Rt, rx0, ry0, xn-1, yn-1);
                float rb = rtap_l(Rt, rx0, ry0, xn,   yn-1);
                float rc = rtap_l(Rt, rx0, ry0, xn+1, yn-1);
                float rd = rtap_l(Rt, rx0, ry0, xn-1, yn);
                float re = rtap_l(Rt, rx0, ry0, xn+1, yn);
                float rf = rtap_l(Rt, rx0, ry0, xn-1, yn+1);
                float rh = rtap_l(Rt, rx0, ry0, xn,   yn+1);
                float ri = rtap_l(Rt, rx0, ry0, xn+1, yn+1);
                r0 = -3.f*ra + 3.f*rc + 10.f*rd + 10.f*re - 3.f*rf + 3.f*ri;
                r1 = -3.f*ra + 10.f*rb - 3.f*rc + 3.f*rf + 10.f*rh + 3.f*ri;
            }
            gmaps[((size_t)(12 + bc*2+0))*HW + p] = r0;
            gmaps[((size_t)(12 + bc*2+1))*HW + p] = r1;
            mn0 = fminf(mn0, g0); mx0 = fmaxf(mx0, g0);
            mn1 = fminf(mn1, g1); mx1 = fmaxf(mx1, g1);
            mn2 = fminf(mn2, r0); mx2 = fmaxf(mx2, r0);
            mn3 = fminf(mn3, r1); mx3 = fmaxf(mx3, r1);
        }
        slo[0][tid] = mn0; shi[0][tid] = mx0;
        slo[1][tid] = mn1; shi[1][tid] = mx1;
        slo[2][tid] = mn2; shi[2][tid] = mx2;
        slo[3][tid] = mn3; shi[3][tid] = mx3;
        __syncthreads();
        for (int off = 128; off > 0; off >>= 1) {
            if (tid < off) {
                #pragma unroll
                for (int k = 0; k < 4; ++k) {
                    slo[k][tid] = fminf(slo[k][tid], slo[k][tid + off]);
                    shi[k][tid] = fmaxf(shi[k][tid], shi[k][tid + off]);
                }
            }
            __syncthreads();
        }
        if (tid < 4) {
            int m = (tid < 2) ? (bc*2 + tid) : (12 + bc*2 + (tid - 2));
            pmin[m * NBLK + tile] = slo[tid][0];
            pmax[m * NBLK + tile] = shi[tid][0];
        }
    } else {
        // ---- regchist role: gy=(b*3+g)*3+c, split bx; int32 labels ----
        int u = t - 1536;
        int gy = u >> 5;
        int bx = u & 31;
        int c = gy % 3;
        int bg = gy / 3;
        int b = bg / 3;
        unsigned* cnt = (unsigned*)smem;             // 6400
        unsigned* rcnt = cnt + NSEG * 25;            // 256
        int* sxmin = (int*)(rcnt + NSEG);            // 4x256 (total 30720 B)
        int* sxmax = sxmin + NSEG;
        int* symin = sxmax + NSEG;
        int* symax = symin + NSEG;
        bool do_reg = (c == 0);
        for (int i = tid; i < NSEG * 25; i += 256) cnt[i] = 0;
        if (do_reg) {
            rcnt[tid] = 0; sxmin[tid] = INT_MAX; sxmax[tid] = INT_MIN;
            symin[tid] = INT_MAX; symax[tid] = INT_MIN;
        }
        __syncthreads();
        const float4* ip = (const float4*)(img + ((size_t)b * 3 + c) * HW);
        const int4* lp = (const int4*)(lab + (size_t)bg * HW);
        for (int i = bx * 256 + tid; i < HW / 4; i += 256 * CHP) {
            float4 v4 = ip[i];
            int4 l4 = lp[i];
            int l0 = l4.x & 255, l1 = l4.y & 255, l2 = l4.z & 255, l3 = l4.w & 255;
            int b0 = (int)((float)l0 * 25.0f + v4.x * 24.0f);
            int b1 = (int)((float)l1 * 25.0f + v4.y * 24.0f);
            int b2 = (int)((float)l2 * 25.0f + v4.z * 24.0f);
            int b3 = (int)((float)l3 * 25.0f + v4.w * 24.0f);
            b0 = min(max(b0, 0), 6399); b1 = min(max(b1, 0), 6399);
            b2 = min(max(b2, 0), 6399); b3 = min(max(b3, 0), 6399);
            atomicAdd(&cnt[b0], 1u); atomicAdd(&cnt[b1], 1u);
            atomicAdd(&cnt[b2], 1u); atomicAdd(&cnt[b3], 1u);
            if (do_reg) {
                int p = i << 2;
                int y = p >> 9, x = p & 511;
                atomicAdd(&rcnt[l0], 1u); atomicAdd(&rcnt[l1], 1u);
                atomicAdd(&rcnt[l2], 1u); atomicAdd(&rcnt[l3], 1u);
                atomicMin(&sxmin[l0], x);     atomicMax(&sxmax[l0], x);
                atomicMin(&sxmin[l1], x + 1); atomicMax(&sxmax[l1], x + 1);
                atomicMin(&sxmin[l2], x + 2); atomicMax(&sxmax[l2], x + 2);
                atomicMin(&sxmin[l3], x + 3); atomicMax(&sxmax[l3], x + 3);
                atomicMin(&symin[l0], y); atomicMax(&symax[l0], y);
                atomicMin(&symin[l1], y); atomicMax(&symax[l1], y);
                atomicMin(&symin[l2], y); atomicMax(&symax[l2], y);
                atomicMin(&symin[l3], y); atomicMax(&symax[l3], y);
            }
        }
        __syncthreads();
        unsigned* dst = chp + ((size_t)gy * CHP + bx) * 6400;
        for (int i = tid; i < NSEG * 25; i += 256) dst[i] = cnt[i];
        if (do_reg) {
            size_t pi = (size_t)(bg * CHP + bx) * NSEG + tid;
            rsp[pi] = rcnt[tid];
            bxmin[pi] = sxmin[tid]; bxmax[pi] = sxmax[tid];
            bymin[pi] = symin[tid]; bymax[pi] = symax[tid];
        }
    }
}

// ==== K2: thist (blocks 0..383) || ch-final + rs + xywh (blocks 384..639) ====
// ch-final path depends only on K1 partials -> rides along to fill idle CUs.
__global__ __launch_bounds__(256) void k_mid(
    const float* __restrict__ maps, const unsigned char* __restrict__ lab8,
    const float* __restrict__ pmin, const float* __restrict__ pmax,
    unsigned* __restrict__ thp, const unsigned* __restrict__ chp,
    const unsigned* __restrict__ rsp, const int* __restrict__ bxmin,
    const int* __restrict__ bxmax, const int* __restrict__ bymin,
    const int* __restrict__ bymax, float* __restrict__ out)
{
    __shared__ __align__(16) char smem[63488];
    int t = blockIdx.x;
    int tid = threadIdx.x;
    if (t < 384) {
        unsigned (*cnt)[5120] = (unsigned (*)[5120])smem;   // 3*5120 u32
        float* slo = (float*)(smem + 61440);                // 256 f
        float* shi = slo + 256;                             // 256 f
        int split = t & 15;
        int m = t >> 4;
        int base = m / 12;
        int rest = m - base * 12;
        int bc = rest >> 1;
        int d = rest & 1;
        int b = bc / 3;
        float mn, mx;
        mm_of_map(pmin, pmax, m, slo, shi, mn, mx);
        for (int i = tid; i < 3 * 5120; i += 256) ((unsigned*)cnt)[i] = 0;
        __syncthreads();
        float hminp = fmaxf(mn, 0.f), denp = fmaxf(mx, 0.f) - hminp;
        float hminn = fminf(mn, 0.f), denn = fminf(mx, 0.f) - hminn;
        const float4* src = (const float4*)(maps + (size_t)m * HW);
        const unsigned* l0p = (const unsigned*)(lab8 + (size_t)(b * 3 + 0) * HW);
        const unsigned* l1p = (const unsigned*)(lab8 + (size_t)(b * 3 + 1) * HW);
        const unsigned* l2p = (const unsigned*)(lab8 + (size_t)(b * 3 + 2) * HW);
        for (int i = split * 256 + tid; i < HW / 4; i += 256 * THP) {
            float4 v4 = src[i];
            unsigned la0 = l0p[i], la1 = l1p[i], la2 = l2p[i];
#define TH1(V, SH)                                                     \
            {                                                          \
                float v = (V);                                         \
                bool ge = (v >= 0.f);                                  \
                float hm = ge ? hminp : hminn;                         \
                float dn = ge ? denp : denn;                           \
                float t9 = ((v - hm) / dn) * 9.0f;                     \
                int off = ge ? 0 : 2560;                               \
                int bi0 = (int)((float)((la0 >> SH) & 255u) * 10.0f + t9); \
                int bi1 = (int)((float)((la1 >> SH) & 255u) * 10.0f + t9); \
                int bi2 = (int)((float)((la2 >> SH) & 255u) * 10.0f + t9); \
                bi0 = min(max(bi0, 0), 2559);                          \
                bi1 = min(max(bi1, 0), 2559);                          \
                bi2 = min(max(bi2, 0), 2559);                          \
                atomicAdd(&cnt[0][off + bi0], 1u);                     \
                atomicAdd(&cnt[1][off + bi1], 1u);                     \
                atomicAdd(&cnt[2][off + bi2], 1u);                     \
            }
            TH1(v4.x, 0) TH1(v4.y, 8) TH1(v4.z, 16) TH1(v4.w, 24)
#undef TH1
        }
        __syncthreads();
        int r = (bc * 2 + d) * 2 + base;   // inverse of k_thfinal's gy decode
        for (int gi = 0; gi < 3; ++gi) {
            unsigned* dst = thp + ((size_t)((r * 3 + gi) * THP + split)) * 5120;
            for (int i = tid; i < 5120; i += 256) dst[i] = cnt[gi][i];
        }
    } else {
        // ch-final: block handles s=j for all 6 bgs; threads 0..74 ch bins,
        // thread 75 rs/bbox/xywh. rs computed redundantly (no syncs needed).
        int j = t - 384;
        if (tid < 76) {
            for (int bg = 0; bg < 6; ++bg) {
                int seg = bg * 256 + j;
                unsigned rs = 0;
                const unsigned* rp = rsp + (size_t)(bg * CHP) * NSEG + j;
                #pragma unroll 4
                for (int p = 0; p < CHP; ++p) rs += rp[p * NSEG];
                float rsf = (float)rs;
                if (tid < 75) {
                    int c = tid / 25, cb = tid - c * 25;
                    float cd = 3.0f * rsf;
                    const unsigned* src = chp + ((size_t)((bg * 3 + c) * CHP)) * 6400 + j * 25 + cb;
                    unsigned sum = 0;
                    #pragma unroll 4
                    for (int p = 0; p < CHP; ++p) sum += src[(size_t)p * 6400];
                    out[CH_OFF + (size_t)seg * 75 + tid] = (float)sum / cd;
                } else {
                    out[seg] = rsf;
                    int xmn = INT_MAX, xmx = INT_MIN, ymn = INT_MAX, ymx = INT_MIN;
                    const int* p0 = bxmin + (size_t)(bg * CHP) * NSEG + j;
                    const int* p1 = bxmax + (size_t)(bg * CHP) * NSEG + j;
                    const int* p2 = bymin + (size_t)(bg * CHP) * NSEG + j;
                    const int* p3 = bymax + (size_t)(bg * CHP) * NSEG + j;
                    for (int p = 0; p < CHP; ++p) {
                        xmn = min(xmn, p0[p * NSEG]); xmx = max(xmx, p1[p * NSEG]);
                        ymn = min(ymn, p2[p * NSEG]); ymx = max(ymx, p3[p * NSEG]);
                    }
                    if (!(rsf > 0.f)) { xmn = IW; ymn = IW; xmx = 0; ymx = 0; }
                    float* xy = out + XY_OFF + (size_t)seg * 4;
                    xy[0] = (float)xmn; xy[1] = (float)ymn;
                    xy[2] = (float)(xmx - xmn); xy[3] = (float)(ymx - ymn);
                }
            }
        }
    }
}

// ==== K3: th partial-reduce + sign-completion + normalize (72 blocks) ====
__global__ __launch_bounds__(256) void k_thfinal(
    const unsigned* __restrict__ thp,
    const float* __restrict__ pmin, const float* __restrict__ pmax,
    float* __restrict__ out)
{
    __shared__ unsigned hist[5120];
    __shared__ float slo[256], shi[256];
    int tid = threadIdx.x;
    int gy = blockIdx.x;
    int gi = gy % 3; int r = gy / 3; int base = r & 1;
    int bd = r >> 1; int d = bd & 1; int bc = bd >> 1;
    int b = bc / 3, c = bc - b * 3;
    int m = base * 12 + bc * 2 + d;
    float mn, mx;
    mm_of_map(pmin, pmax, m, slo, shi, mn, mx);
    for (int i = tid; i < 5120; i += 256) {
        unsigned s = 0;
        for (int p = 0; p < THP; ++p) s += thp[((size_t)(gy * THP + p)) * 5120 + i];
        hist[i] = s;
    }
    __syncthreads();
    {
        int l = tid;   // one thread per label: sign-completion
        unsigned nge = 0;
        for (int tb = 0; tb < 10; ++tb) nge += hist[l * 10 + tb];   // v>=0 pixel count
        float rsf = out[(b * 3 + gi) * NSEG + l];
        unsigned rsu = (unsigned)rsf;
        unsigned nlt = (rsu >= nge) ? (rsu - nge) : 0u;              // v<0 pixel count
        float hminp = fmaxf(mn, 0.f), denp = fmaxf(mx, 0.f) - hminp;
        float hminn = fminf(mn, 0.f), denn = fminf(mx, 0.f) - hminn;
        float la = (float)l;
        float tp0 = ((0.0f - hminp) / denp) * 9.0f;   // pos bin of clipped (v<0) pixels
        float tn0 = ((0.0f - hminn) / denn) * 9.0f;   // neg bin of clipped (v>=0) pixels
        int bp = (int)(la * 10.0f + tp0); bp = min(max(bp, 0), 2559);
        int bn = (int)(la * 10.0f + tn0); bn = min(max(bn, 0), 2559);
        if (nlt) atomicAdd(&hist[bp], nlt);
        if (nge) atomicAdd(&hist[2560 + bn], nge);
    }
    __syncthreads();
    for (int i = tid; i < 5120; i += 256) {
        int pos = (i < 2560);
        int rr = pos ? i : i - 2560;
        int seg = rr / 10, tb = rr - seg * 10;
        int tt = base * 4 + (pos ? 0 : 2) + d;
        float rsf = out[(b * 3 + gi) * NSEG + seg];
        out[TH_OFF + ((size_t)((b * 3 + gi) * NSEG + seg) * 3 + c) * 80 + tt * 10 + tb] =
            (float)hist[i] / (24.0f * rsf);
    }
}

extern "C" void kernel_launch(void* const* d_in, const int* in_sizes, int n_in,
                              void* d_out, int out_size, void* d_ws, size_t ws_size,
                              hipStream_t stream) {
    const float* img = (const float*)d_in[0];
    const int* lab = (const int*)d_in[1];
    float* out = (float*)d_out;

    float* gmaps = (float*)d_ws;                        // 24 maps * 262144 f32 (25.2 MB)
    float* pmin = gmaps + (size_t)24 * HW;              // 24*NBLK
    float* pmax = pmin + 24 * NBLK;
    unsigned* thp = (unsigned*)(pmax + 24 * NBLK);      // 72*THP*5120 u32 (~23.6 MB)
    unsigned* chp = thp + (size_t)72 * THP * 5120;      // 18*CHP*6400 u32 (~14.7 MB)
    unsigned char* lab8 = (unsigned char*)(chp + (size_t)18 * CHP * 6400);  // 6*HW u8 (1.5 MB)
    unsigned* rsp = (unsigned*)(lab8 + (size_t)6 * HW); // 6*CHP*256 u32 partial region sizes
    int* bxmin = (int*)(rsp + 6 * CHP * NSEG);
    int* bxmax = bxmin + 6 * CHP * NSEG;
    int* bymin = bxmax + 6 * CHP * NSEG;
    int* bymax = bymin + 6 * CHP * NSEG;

    hipLaunchKernelGGL(k_front, dim3(1536 + 18 * CHP), dim3(256), 0, stream,
                       img, lab, gmaps, pmin, pmax, lab8, chp, rsp, bxmin, bxmax, bymin, bymax);
    hipLaunchKernelGGL(k_mid, dim3(384 + 256), dim3(256), 0, stream,
                       gmaps, lab8, pmin, pmax, thp, chp, rsp, bxmin, bxmax, bymin, bymax, out);
    hipLaunchKernelGGL(k_thfinal, dim3(72), dim3(256), 0, stream, thp, pmin, pmax, out);
}

// Round 4
// 131.761 us; speedup vs baseline: 1.4200x; 1.4200x over previous
//
#include <hip/hip_runtime.h>
#include <climits>

#define HW 262144          // 512*512
#define IW 512
#define RN 725             // virtual rotated canvas side
#define NSEG 256
#define CH_OFF 1536
#define TH_OFF 116736
#define XY_OFF 485376
#define NBLK 256           // k_grad tiles per plane; minmax partial count
#define THP 24             // pixel splits in k_thist (r18: 16->24, full residency)
#define CHP 32             // pixel splits in k_regchist

// grad tile geometry (r16): output tile 64x16; rotated source box 24x72 at (-156,-156).
#define ASTR 67
#define RSTR 73
#define ROFF 156

static __device__ __forceinline__ float rtap_l(const float* __restrict__ Rt,
                                               int rx0, int ry0, int cx, int cy) {
    if (cx < 0 || cx >= RN || cy < 0 || cy >= RN) return 0.f;
    const float cs = 0.7071067811865476f;
    float xg = (float)cx - 362.0f;
    float yg = (float)cy - 362.0f;
    float xi = cs * xg - cs * yg + 255.5f;
    float yi = cs * xg + cs * yg + 255.5f;
    int xs = (int)rintf(xi);
    int ys = (int)rintf(yi);
    if (xs < 0 || xs >= IW || ys < 0 || ys >= IW) return 0.f;
    return Rt[(ys - ry0) * RSTR + (xs - rx0)];
}

// block-level min/max of map m's NBLK partials; all threads get (mn,mx)
static __device__ __forceinline__ void mm_of_map(const float* __restrict__ pmin,
                                                 const float* __restrict__ pmax,
                                                 int m, float* slo, float* shi,
                                                 float& mn, float& mx) {
    int tid = threadIdx.x;
    float lo = 3.4e38f, hi = -3.4e38f;
    for (int i = tid; i < NBLK; i += 256) {
        lo = fminf(lo, pmin[m * NBLK + i]);
        hi = fmaxf(hi, pmax[m * NBLK + i]);
    }
    slo[tid] = lo; shi[tid] = hi;
    __syncthreads();
    for (int off = 128; off > 0; off >>= 1) {
        if (tid < off) {
            slo[tid] = fminf(slo[tid], slo[tid + off]);
            shi[tid] = fmaxf(shi[tid], shi[tid + off]);
        }
        __syncthreads();
    }
    mn = slo[0]; mx = shi[0];
    __syncthreads();
}

// ---- gradients, LDS-tiled (r16) + min/max partials + init chores + u8 pack ----
// r18: reverted to the standalone r2 form (20KB LDS -> 8 blocks/CU; the r17
// merge with regchist forced 30KB LDS on grad blocks and cost occupancy).
__global__ __launch_bounds__(256) void k_grad(
    const float* __restrict__ img, const int* __restrict__ lab,
    float* __restrict__ gmaps,
    float* __restrict__ pmin, float* __restrict__ pmax,
    float* __restrict__ out, int* __restrict__ bbmin, int* __restrict__ bbmax,
    unsigned char* __restrict__ lab8)
{
    int t = blockIdx.x;        // tile index: tx0=(t&7)*64, ty0=(t>>3)*16
    int bc = blockIdx.y;
    int tid = threadIdx.x;
    // init chores for later-launched consumers (stream order covers visibility)
    if (bc == 0 && t < 6) {                     // zero rs: 6*256 == 1536
        out[t * 256 + tid] = 0.0f;
    } else if (bc == 1 && t < 12) {             // bbox init: 12*256 == 2*3072
        int i = t * 256 + tid;
        bbmin[i] = INT_MAX;
        bbmax[i] = INT_MIN;
    }
    // u8 label pack: 256 blocks * 256 thr * 4 labels == HW per plane
    {
        int i = t * 256 + tid;
        int4 l = ((const int4*)(lab + (size_t)bc * HW))[i];
        unsigned v = (unsigned)(l.x & 255) | ((unsigned)(l.y & 255) << 8) |
                     ((unsigned)(l.z & 255) << 16) | ((unsigned)(l.w & 255) << 24);
        ((unsigned*)(lab8 + (size_t)bc * HW))[i] = v;
    }
    __shared__ float At[18 * ASTR];
    __shared__ float Rt[24 * RSTR];
    __shared__ float slo[4][256], shi[4][256];
    int tx0 = (t & 7) << 6;
    int ty0 = (t >> 3) << 4;
    const float* im = img + (size_t)bc * HW;
    int lane = tid & 63, wr = tid >> 6;
    // stage direct tile: rows ty0-1..ty0+16 (18), cols tx0-1..tx0+64 (66)
    for (int r = wr; r < 18; r += 4) {
        int gy = ty0 - 1 + r;
        bool yok = (gy >= 0 && gy < IW);
        int gx = tx0 - 1 + lane;
        At[r * ASTR + lane] = (yok && gx >= 0 && gx < IW) ? im[gy * IW + gx] : 0.f;
        if (lane < 2) {
            int gx2 = gx + 64;
            At[r * ASTR + lane + 64] = (yok && gx2 >= 0 && gx2 < IW) ? im[gy * IW + gx2] : 0.f;
        }
    }
    // stage rot tile: rows ty0-156..ty0-133 (24), cols tx0-156..tx0-85 (72)
    for (int r = wr; r < 24; r += 4) {
        int gy = ty0 - ROFF + r;
        bool yok = (gy >= 0 && gy < IW);
        int gx = tx0 - ROFF + lane;
        Rt[r * RSTR + lane] = (yok && gx >= 0 && gx < IW) ? im[gy * IW + gx] : 0.f;
        if (lane < 8) {
            int gx2 = gx + 64;
            Rt[r * RSTR + lane + 64] = (yok && gx2 >= 0 && gx2 < IW) ? im[gy * IW + gx2] : 0.f;
        }
    }
    __syncthreads();
    const float cs = 0.7071067811865476f;  // cos(-45); sin(-45) = -cs
    int rx0 = tx0 - ROFF, ry0 = ty0 - ROFF;
    float mn0 = 3.4e38f, mx0 = -3.4e38f, mn1 = 3.4e38f, mx1 = -3.4e38f;
    float mn2 = 3.4e38f, mx2 = -3.4e38f, mn3 = 3.4e38f, mx3 = -3.4e38f;
    #pragma unroll
    for (int it = 0; it < 4; ++it) {
        int ly = wr * 4 + it;              // 0..15
        int x = tx0 + lane, y = ty0 + ly;
        int p = y * IW + x;
        const float* Ar = At + ly * ASTR + lane;
        float a  = Ar[0],            b2 = Ar[1],            c2 = Ar[2];
        float d2 = Ar[ASTR],                                 e2 = Ar[ASTR + 2];
        float f2 = Ar[2 * ASTR],     h2 = Ar[2 * ASTR + 1], i9 = Ar[2 * ASTR + 2];
        float g0 = -3.f*a + 3.f*c2 + 10.f*d2 + 10.f*e2 - 3.f*f2 + 3.f*i9;
        float g1 = -3.f*a + 10.f*b2 - 3.f*c2 + 3.f*f2 + 10.f*h2 + 3.f*i9;
        gmaps[((size_t)(bc*2+0))*HW + p] = g0;
        gmaps[((size_t)(bc*2+1))*HW + p] = g1;
        float xgc = (float)(x + 105) - 512.5f;
        float ygc = (float)(y + 105) - 512.5f;
        float t1 = cs * xgc, t2 = cs * ygc;
        float xi = (t1 + t2) + 362.0f;
        float yi = (-t1 + t2) + 362.0f;
        int xn = (int)rintf(xi);
        int yn = (int)rintf(yi);
        float r0 = 0.f, r1 = 0.f;
        if (xn >= 0 && xn < RN && yn >= 0 && yn < RN) {
            float ra = rtap_l(Rt, rx0, ry0, xn-1, yn-1);
            float rb = rtap_l(Rt, rx0, ry0, xn,   yn-1);
            float rc = rtap_l(Rt, rx0, ry0, xn+1, yn-1);
            float rd = rtap_l(Rt, rx0, ry0, xn-1, yn);
            float re = rtap_l(Rt, rx0, ry0, xn+1, yn);
            float rf = rtap_l(Rt, rx0, ry0, xn-1, yn+1);
            float rh = rtap_l(Rt, rx0, ry0, xn,   yn+1);
            float ri = rtap_l(Rt, rx0, ry0, xn+1, yn+1);
            r0 = -3.f*ra + 3.f*rc + 10.f*rd + 10.f*re - 3.f*rf + 3.f*ri;
            r1 = -3.f*ra + 10.f*rb - 3.f*rc + 3.f*rf + 10.f*rh + 3.f*ri;
        }
        gmaps[((size_t)(12 + bc*2+0))*HW + p] = r0;
        gmaps[((size_t)(12 + bc*2+1))*HW + p] = r1;
        mn0 = fminf(mn0, g0); mx0 = fmaxf(mx0, g0);
        mn1 = fminf(mn1, g1); mx1 = fmaxf(mx1, g1);
        mn2 = fminf(mn2, r0); mx2 = fmaxf(mx2, r0);
        mn3 = fminf(mn3, r1); mx3 = fmaxf(mx3, r1);
    }
    slo[0][tid] = mn0; shi[0][tid] = mx0;
    slo[1][tid] = mn1; shi[1][tid] = mx1;
    slo[2][tid] = mn2; shi[2][tid] = mx2;
    slo[3][tid] = mn3; shi[3][tid] = mx3;
    __syncthreads();
    for (int off = 128; off > 0; off >>= 1) {
        if (tid < off) {
            #pragma unroll
            for (int k = 0; k < 4; ++k) {
                slo[k][tid] = fminf(slo[k][tid], slo[k][tid + off]);
                shi[k][tid] = fmaxf(shi[k][tid], shi[k][tid + off]);
            }
        }
        __syncthreads();
    }
    if (tid < 4) {
        int m = (tid < 2) ? (bc*2 + tid) : (12 + bc*2 + (tid - 2));
        pmin[m * NBLK + t] = slo[tid][0];
        pmax[m * NBLK + t] = shi[tid][0];
    }
}

// ---- color hist (partial write, NO atomic flush) + (c==0) region sizes & bbox ----
__global__ __launch_bounds__(256) void k_regchist(
    const float* __restrict__ img, const unsigned char* __restrict__ lab8,
    float* __restrict__ rs_out, int* __restrict__ bbmin, int* __restrict__ bbmax,
    unsigned* __restrict__ chp)
{
    __shared__ unsigned cnt[NSEG * 25];
    __shared__ unsigned rcnt[NSEG];
    __shared__ int sxmin[NSEG], sxmax[NSEG], symin[NSEG], symax[NSEG];
    int gy = blockIdx.y;       // (b*3+g)*3 + c
    int c = gy % 3;
    int bg = gy / 3;
    int b = bg / 3;
    int tid = threadIdx.x;
    bool do_reg = (c == 0);
    for (int i = tid; i < NSEG * 25; i += 256) cnt[i] = 0;
    if (do_reg) {
        rcnt[tid] = 0; sxmin[tid] = INT_MAX; sxmax[tid] = INT_MIN;
        symin[tid] = INT_MAX; symax[tid] = INT_MIN;
    }
    __syncthreads();
    const float4* ip = (const float4*)(img + ((size_t)b * 3 + c) * HW);
    const unsigned* lp = (const unsigned*)(lab8 + (size_t)bg * HW);
    int stride = 256 * gridDim.x;
    for (int i = blockIdx.x * 256 + tid; i < HW / 4; i += stride) {
        float4 v4 = ip[i];
        unsigned l4 = lp[i];
        int l0 = l4 & 255, l1 = (l4 >> 8) & 255, l2 = (l4 >> 16) & 255, l3 = l4 >> 24;
        int b0 = (int)((float)l0 * 25.0f + v4.x * 24.0f);
        int b1 = (int)((float)l1 * 25.0f + v4.y * 24.0f);
        int b2 = (int)((float)l2 * 25.0f + v4.z * 24.0f);
        int b3 = (int)((float)l3 * 25.0f + v4.w * 24.0f);
        b0 = min(max(b0, 0), 6399); b1 = min(max(b1, 0), 6399);
        b2 = min(max(b2, 0), 6399); b3 = min(max(b3, 0), 6399);
        atomicAdd(&cnt[b0], 1u); atomicAdd(&cnt[b1], 1u);
        atomicAdd(&cnt[b2], 1u); atomicAdd(&cnt[b3], 1u);
        if (do_reg) {
            int p = i << 2;
            int y = p >> 9, x = p & 511;
            atomicAdd(&rcnt[l0], 1u); atomicAdd(&rcnt[l1], 1u);
            atomicAdd(&rcnt[l2], 1u); atomicAdd(&rcnt[l3], 1u);
            atomicMin(&sxmin[l0], x);     atomicMax(&sxmax[l0], x);
            atomicMin(&sxmin[l1], x + 1); atomicMax(&sxmax[l1], x + 1);
            atomicMin(&sxmin[l2], x + 2); atomicMax(&sxmax[l2], x + 2);
            atomicMin(&sxmin[l3], x + 3); atomicMax(&sxmax[l3], x + 3);
            atomicMin(&symin[l0], y); atomicMax(&symax[l0], y);
            atomicMin(&symin[l1], y); atomicMax(&symax[l1], y);
            atomicMin(&symin[l2], y); atomicMax(&symax[l2], y);
            atomicMin(&symin[l3], y); atomicMax(&symax[l3], y);
        }
    }
    __syncthreads();
    // coalesced partial store: zero atomics
    unsigned* dst = chp + ((size_t)gy * CHP + blockIdx.x) * 6400;
    for (int i = tid; i < NSEG * 25; i += 256) dst[i] = cnt[i];
    if (do_reg) {
        if (rcnt[tid]) atomicAdd(&rs_out[bg * NSEG + tid], (float)rcnt[tid]);
        if (sxmin[tid] != INT_MAX) {
            atomicMin(&bbmin[bg * NSEG + tid], sxmin[tid]);
            atomicMax(&bbmax[bg * NSEG + tid], sxmax[tid]);
            atomicMin(&bbmin[1536 + bg * NSEG + tid], symin[tid]);
            atomicMax(&bbmax[1536 + bg * NSEG + tid], symax[tid]);
        }
    }
}

// ---- texture histogram, high-occupancy (r18): one (map, lab-group) hist/block ----
// r17 evidence: 3-group LDS (63.5KB) capped residency at 2 blocks/CU -> 7%
// occupancy, VALUBusy 10.7%, latency-bound. Now 22.5KB -> 7 blocks/CU (28
// waves/CU); grid 24x72=1728 ~= full single-round residency (7*256=1792).
// Map re-read 3x is L2/L3-resident (r0/r1 null results proved traffic is free).
__global__ __launch_bounds__(256) void k_thist(
    const float* __restrict__ maps, const unsigned char* __restrict__ lab8,
    const float* __restrict__ pmin, const float* __restrict__ pmax,
    unsigned* __restrict__ thp)
{
    __shared__ unsigned cnt[5120];     // [0,2560) pos bins, [2560,5120) neg
    __shared__ float slo[256], shi[256];
    int gy = blockIdx.y;               // [0,72): (r*3 + gi)
    int split = blockIdx.x;            // [0,THP)
    int gi = gy % 3;
    int r = gy / 3;
    int base = r & 1;
    int bd = r >> 1;
    int d = bd & 1;
    int bc = bd >> 1;
    int b = bc / 3;
    int m = base * 12 + bc * 2 + d;
    float mn, mx;
    mm_of_map(pmin, pmax, m, slo, shi, mn, mx);
    for (int i = threadIdx.x; i < 5120; i += 256) cnt[i] = 0;
    __syncthreads();
    float hminp = fmaxf(mn, 0.f), denp = fmaxf(mx, 0.f) - hminp;
    float hminn = fminf(mn, 0.f), denn = fminf(mx, 0.f) - hminn;
    const float4* src = (const float4*)(maps + (size_t)m * HW);
    const unsigned* lp = (const unsigned*)(lab8 + (size_t)(b * 3 + gi) * HW);
    for (int i = split * 256 + threadIdx.x; i < HW / 4; i += 256 * THP) {
        float4 v4 = src[i];
        unsigned l4 = lp[i];
#define TH1(V, SH)                                                     \
        {                                                              \
            float v = (V);                                             \
            bool ge = (v >= 0.f);                                      \
            float hm = ge ? hminp : hminn;                             \
            float dn = ge ? denp : denn;                               \
            float t9 = ((v - hm) / dn) * 9.0f;                         \
            int bi = (int)((float)((l4 >> SH) & 255u) * 10.0f + t9);   \
            bi = min(max(bi, 0), 2559);                                \
            atomicAdd(&cnt[(ge ? 0 : 2560) + bi], 1u);                 \
        }
        TH1(v4.x, 0) TH1(v4.y, 8) TH1(v4.z, 16) TH1(v4.w, 24)
#undef TH1
    }
    __syncthreads();
    unsigned* dst = thp + ((size_t)(gy * THP + split)) * 5120;
    for (int i = threadIdx.x; i < 5120; i += 256) dst[i] = cnt[i];
}

// ---- fused final: th chunked-reduce + sign-completion + normalize (bx<288);
//      ch partial-reduce + normalize + xywh (else) ----
// r18: th-reduce split into 4 chunks of 64 labels per gy -> 288 blocks (was 72).
// Sign-completion bins are l*10+{0,9} (mn<0<mx for every Scharr map) -> chunk-local.
__global__ __launch_bounds__(256) void k_thfinal(
    const unsigned* __restrict__ thp, const unsigned* __restrict__ chp,
    const float* __restrict__ pmin, const float* __restrict__ pmax,
    const int* __restrict__ bbmin, const int* __restrict__ bbmax,
    float* __restrict__ out)
{
    int tid = threadIdx.x;
    int bx = blockIdx.x;
    if (bx < 288) {
        __shared__ unsigned hist[1280];    // [0,640) pos, [640,1280) neg, 64 labels
        __shared__ float slo[256], shi[256];
        int gy = bx >> 2;
        int ck = bx & 3;
        int l0 = ck << 6;                  // first label of chunk
        int gi = gy % 3; int r = gy / 3; int base = r & 1;
        int bd = r >> 1; int d = bd & 1; int bc = bd >> 1;
        int b = bc / 3, c = bc - b * 3;
        int m = base * 12 + bc * 2 + d;
        float mn, mx;
        mm_of_map(pmin, pmax, m, slo, shi, mn, mx);
        int g0off = l0 * 10;
        for (int i = tid; i < 1280; i += 256) {
            int g = (i < 640) ? (g0off + i) : (2560 + g0off + (i - 640));
            unsigned s = 0;
            #pragma unroll 4
            for (int p = 0; p < THP; ++p) s += thp[((size_t)(gy * THP + p)) * 5120 + g];
            hist[i] = s;
        }
        __syncthreads();
        if (tid < 64) {
            int l = l0 + tid;   // this chunk's labels: sign-completion
            unsigned nge = 0;
            for (int tb = 0; tb < 10; ++tb) nge += hist[tid * 10 + tb];  // v>=0 count
            float rsf = out[(b * 3 + gi) * NSEG + l];
            unsigned rsu = (unsigned)rsf;
            unsigned nlt = (rsu >= nge) ? (rsu - nge) : 0u;              // v<0 count
            float hminp = fmaxf(mn, 0.f), denp = fmaxf(mx, 0.f) - hminp;
            float hminn = fminf(mn, 0.f), denn = fminf(mx, 0.f) - hminn;
            float la = (float)l;
            float tp0 = ((0.0f - hminp) / denp) * 9.0f;  // pos bin of clipped (v<0)
            float tn0 = ((0.0f - hminn) / denn) * 9.0f;  // neg bin of clipped (v>=0)
            int bp = (int)(la * 10.0f + tp0); bp = min(max(bp, 0), 2559);
            int bn = (int)(la * 10.0f + tn0); bn = min(max(bn, 0), 2559);
            if (nlt && bp >= g0off && bp < g0off + 640) atomicAdd(&hist[bp - g0off], nlt);
            if (nge && bn >= g0off && bn < g0off + 640) atomicAdd(&hist[640 + bn - g0off], nge);
        }
        __syncthreads();
        for (int i = tid; i < 1280; i += 256) {
            int pos = (i < 640);
            int rr = pos ? i : i - 640;
            int seg = l0 + rr / 10, tb = rr % 10;
            int tt = base * 4 + (pos ? 0 : 2) + d;
            float rsf = out[(b * 3 + gi) * NSEG + seg];
            out[TH_OFF + ((size_t)((b * 3 + gi) * NSEG + seg) * 3 + c) * 80 + tt * 10 + tb] =
                (float)hist[i] / (24.0f * rsf);
        }
    } else {
        for (int seg = bx - 288; seg < 1536; seg += (gridDim.x - 288)) {
            int bg = seg >> 8;        // seg = bg*256 + s
            int s = seg & 255;
            float rsf = out[seg];
            float cd = 3.0f * rsf;
            float* ch = out + CH_OFF + (size_t)seg * 75;
            // reduce CHP partials for this seg's 75 (c,cb) bins; coalesced 25-bursts
            for (int i = tid; i < 75; i += 256) {
                int c = i / 25, cb = i - c * 25;
                unsigned sum = 0;
                const unsigned* src = chp + ((size_t)(bg * 3 + c) * CHP) * 6400 + s * 25 + cb;
                #pragma unroll 4
                for (int p = 0; p < CHP; ++p) sum += src[(size_t)p * 6400];
                ch[i] = (float)sum / cd;
            }
            if (tid == 0) {
                int xmin, xmax, ymin, ymax;
                if (rsf > 0.f) {
                    xmin = bbmin[seg]; ymin = bbmin[1536 + seg];
                    xmax = bbmax[seg]; ymax = bbmax[1536 + seg];
                } else {
                    xmin = IW; ymin = IW; xmax = 0; ymax = 0;
                }
                float* xy = out + XY_OFF + (size_t)seg * 4;
                xy[0] = (float)xmin; xy[1] = (float)ymin;
                xy[2] = (float)(xmax - xmin); xy[3] = (float)(ymax - ymin);
            }
        }
    }
}

extern "C" void kernel_launch(void* const* d_in, const int* in_sizes, int n_in,
                              void* d_out, int out_size, void* d_ws, size_t ws_size,
                              hipStream_t stream) {
    const float* img = (const float*)d_in[0];
    const int* lab = (const int*)d_in[1];
    float* out = (float*)d_out;

    float* gmaps = (float*)d_ws;                        // 24 maps * 262144 f32 (25.2 MB)
    float* pmin = gmaps + (size_t)24 * HW;              // 24*NBLK
    float* pmax = pmin + 24 * NBLK;
    int* bbmin = (int*)(pmax + 24 * NBLK);              // 3072: [xmin(1536), ymin(1536)]
    int* bbmax = bbmin + 3072;                          // 3072: [xmax(1536), ymax(1536)]
    unsigned* thp = (unsigned*)(bbmax + 3072);          // 72*THP*5120 u32 (~35.4 MB)
    unsigned* chp = thp + (size_t)72 * THP * 5120;      // 18*CHP*6400 u32 (~14.7 MB)
    unsigned char* lab8 = (unsigned char*)(chp + (size_t)18 * CHP * 6400);  // 6*HW u8 (1.5 MB)

    hipLaunchKernelGGL(k_grad, dim3(NBLK, 6), dim3(256), 0, stream,
                       img, lab, gmaps, pmin, pmax, out, bbmin, bbmax, lab8);
    hipLaunchKernelGGL(k_regchist, dim3(CHP, 18), dim3(256), 0, stream,
                       img, lab8, out, bbmin, bbmax, chp);
    hipLaunchKernelGGL(k_thist, dim3(THP, 72), dim3(256), 0, stream, gmaps, lab8, pmin, pmax, thp);
    hipLaunchKernelGGL(k_thfinal, dim3(288 + 256), dim3(256), 0, stream, thp, chp, pmin, pmax, bbmin, bbmax, out);
}